// Round 10
// baseline (2110.469 us; speedup 1.0000x reference)
//
#include <hip/hip_runtime.h>
#include <hip/hip_bf16.h>

// Problem constants
#define NB    65536      // batch rows
#define KDIM  1024       // reduction dim for all projections
#define NDIM  1024       // output dim per projection

// 256x256 GEMM geometry, BK=32, quad-buffered ring (depth-3 prefetch)
#define BM 256
#define BN 256
#define BK 32
#define NT (KDIM / BK)   // 32 K-tiles

typedef float f32x4  __attribute__((ext_vector_type(4)));
typedef float f32x16 __attribute__((ext_vector_type(16)));
typedef short short8 __attribute__((ext_vector_type(8)));
typedef unsigned short ushort8v __attribute__((ext_vector_type(8)));

static __device__ __forceinline__ unsigned short f2bf(float f) {
    union { float f; unsigned u; } v; v.f = f;
    unsigned r = v.u + 0x7FFFu + ((v.u >> 16) & 1u);
    return (unsigned short)(r >> 16);
}
static __device__ __forceinline__ float bf2f(unsigned short h) {
    union { unsigned u; float f; } v; v.u = ((unsigned)h) << 16;
    return v.f;
}

// async global->LDS, 16B per lane. LDS dest = wave-uniform base + lane*16.
static __device__ __forceinline__ void gload16(const unsigned short* g, unsigned short* l) {
    __builtin_amdgcn_global_load_lds(
        (const __attribute__((address_space(1))) unsigned int*)g,
        (__attribute__((address_space(3))) unsigned int*)l, 16, 0, 0);
}

// ---------------------------------------------------------------------------
// fp32 -> bf16 convert, grid-stride, 4 elems/thread/iter
// ---------------------------------------------------------------------------
__global__ __launch_bounds__(256) void f32_to_bf16_k(
    const float* __restrict__ s, unsigned short* __restrict__ d, int n4)
{
    const int stride = gridDim.x * 256;
    for (int i = blockIdx.x * 256 + threadIdx.x; i < n4; i += stride) {
        float4 v = reinterpret_cast<const float4*>(s)[i];
        ushort4 o;
        o.x = f2bf(v.x); o.y = f2bf(v.y); o.z = f2bf(v.z); o.w = f2bf(v.w);
        reinterpret_cast<ushort4*>(d)[i] = o;
    }
}

// ---------------------------------------------------------------------------
// 256x256 GEMM, BK=32, ring-4 LDS depth-3 prefetch (r8 structure, verified).
// Templated on output width NN (1024 single-proj / 2048 fused K|V).
// ---------------------------------------------------------------------------
template<int OUT_F32, int NN>
__global__ __launch_bounds__(512, 2) void gemm256(
    const unsigned short* __restrict__ Ap, const unsigned short* __restrict__ Wp,
    const float* __restrict__ bias, void* __restrict__ Cptr)
{
    constexpr int GN = NN / BN;              // 4 or 8 col tiles
    __shared__ alignas(16) unsigned short lds[4][2][16][512];

    const int t    = threadIdx.x;
    const int lane = t & 63;
    const int wid  = t >> 6;                 // 0..7
    const int wm   = wid >> 2;               // 0..1  (128 rows each)
    const int wn   = wid & 3;                // 0..3  (64 cols each)

    // XCD-chunked swizzle (nwg % 8 == 0)
    const int nwg  = gridDim.x;
    const int cpx  = nwg >> 3;
    const int orig = blockIdx.x;
    const int wgid = (orig & 7) * cpx + (orig >> 3);
    const int bn0  = (wgid & (GN - 1)) * BN;
    const int bm0  = (wgid / GN) * BM;

    const size_t aoff = (size_t)(lane & 15) * KDIM + (lane >> 4) * 8;

#define STAGE_(TAU, SLOT) do {                                                  \
        int _tc = (TAU) < NT ? (TAU) : NT - 1;                                  \
        _Pragma("unroll")                                                       \
        for (int _ab = 0; _ab < 2; ++_ab) {                                     \
            const unsigned short* _b = _ab ? Wp : Ap;                           \
            int _r0 = _ab ? bn0 : bm0;                                          \
            _Pragma("unroll")                                                   \
            for (int _j = 0; _j < 2; ++_j) {                                    \
                int _f = wid * 2 + _j;                                          \
                gload16(_b + (size_t)(_r0 + _f * 16) * KDIM + _tc * BK + aoff,  \
                        &lds[SLOT][_ab][_f][0]);                                \
            }                                                                   \
        }                                                                       \
    } while (0)

    f32x4 acc[8][4];
#pragma unroll
    for (int mi = 0; mi < 8; ++mi)
#pragma unroll
        for (int ni = 0; ni < 4; ++ni)
            acc[mi][ni] = (f32x4){0.f, 0.f, 0.f, 0.f};

    STAGE_(0, 0); STAGE_(1, 1); STAGE_(2, 2);

#pragma unroll 1
    for (int tt = 0; tt < NT; ++tt) {
        const int slot = tt & 3;
        STAGE_(tt + 3, (tt + 3) & 3);
        asm volatile("s_waitcnt vmcnt(12)" ::: "memory");  // stage(tt) landed
        __builtin_amdgcn_s_barrier();

        short8 af[8], bq[4];
#pragma unroll
        for (int mi = 0; mi < 8; ++mi)
            af[mi] = *reinterpret_cast<const short8*>(&lds[slot][0][wm * 8 + mi][lane * 8]);
#pragma unroll
        for (int ni = 0; ni < 4; ++ni)
            bq[ni] = *reinterpret_cast<const short8*>(&lds[slot][1][wn * 4 + ni][lane * 8]);
        __builtin_amdgcn_s_setprio(1);
#pragma unroll
        for (int mi = 0; mi < 8; ++mi)
#pragma unroll
            for (int ni = 0; ni < 4; ++ni)
                acc[mi][ni] = __builtin_amdgcn_mfma_f32_16x16x32_bf16(
                    af[mi], bq[ni], acc[mi][ni], 0, 0, 0);
        __builtin_amdgcn_s_setprio(0);
        __builtin_amdgcn_s_barrier();
    }
    asm volatile("s_waitcnt vmcnt(0)" ::: "memory");
    __builtin_amdgcn_s_barrier();

    // epilogue: LDS bounce -> full-line stores (WRITE_SIZE exact-ideal, r7+)
    const int crow = (lane >> 4) * 4;
    const int ccol = lane & 15;
    if (OUT_F32) {
        float* Cf = (float*)Cptr;
        float* bbf = reinterpret_cast<float*>(&lds[0][0][0][0]);
        float bv[4];
#pragma unroll
        for (int ni = 0; ni < 4; ++ni)
            bv[ni] = bias[bn0 + wn * 64 + ni * 16 + ccol];
#pragma unroll
        for (int p = 0; p < 4; ++p) {
            if (wm == (p >> 1)) {
#pragma unroll
                for (int ml = 0; ml < 4; ++ml)
#pragma unroll
                    for (int ni = 0; ni < 4; ++ni)
#pragma unroll
                        for (int r = 0; r < 4; ++r)
                            bbf[(ml * 16 + crow + r) * 268 + wn * 64 + ni * 16 + ccol]
                                = acc[(p & 1) * 4 + ml][ni][r] + bv[ni];
            }
            __syncthreads();
#pragma unroll
            for (int it = 0; it < 8; ++it) {
                int lrow = wid * 8 + it;
                f32x4 v = *reinterpret_cast<const f32x4*>(&bbf[lrow * 268 + lane * 4]);
                *reinterpret_cast<f32x4*>(
                    &Cf[(size_t)(bm0 + p * 64 + lrow) * NN + bn0 + lane * 4]) = v;
            }
            __syncthreads();
        }
    } else {
        unsigned short* Cb = (unsigned short*)Cptr;
        unsigned short* bb = &lds[0][0][0][0];
#pragma unroll
        for (int p = 0; p < 2; ++p) {
            if (wm == p) {
#pragma unroll
                for (int ml = 0; ml < 8; ++ml)
#pragma unroll
                    for (int ni = 0; ni < 4; ++ni)
#pragma unroll
                        for (int r = 0; r < 4; ++r)
                            bb[(ml * 16 + crow + r) * 264 + wn * 64 + ni * 16 + ccol]
                                = f2bf(acc[ml][ni][r]);
            }
            __syncthreads();
#pragma unroll
            for (int it = 0; it < 8; ++it) {
                int lrow = wid * 16 + it * 2 + (lane >> 5);
                int lcol = (lane & 31) * 8;
                ushort8v v = *reinterpret_cast<const ushort8v*>(&bb[lrow * 264 + lcol]);
                *reinterpret_cast<ushort8v*>(
                    &Cb[(size_t)(bm0 + p * 128 + lrow) * NN + bn0 + lcol]) = v;
            }
            __syncthreads();
        }
    }
#undef STAGE_
}

// ---------------------------------------------------------------------------
// DIAGNOSTIC PROBES (write to dead scratch; launched after all real work).
// Same window structure as gemm256's main loop, grid=256 (1 block/CU).
// VARIANT: 0 full | 1 no-stage | 2 no-vmcnt-wait | 3 32x32-MFMA-shaped.
// All variants keep reads->MFMA->acc->store live (no DCE). Timing only;
// V1/V2/V3 outputs are numerically garbage by design.
// ---------------------------------------------------------------------------
template<int VARIANT, int REPS>
__global__ __launch_bounds__(512, 2) void gemm_probe(
    const unsigned short* __restrict__ Ap, const unsigned short* __restrict__ Wp,
    float* __restrict__ Cout)
{
    __shared__ alignas(16) unsigned short lds[4][2][16][512];
    const int t    = threadIdx.x;
    const int lane = t & 63;
    const int wid  = t >> 6;
    const int wm   = wid >> 2;
    const int wn   = wid & 3;
    const int bn0  = (blockIdx.x & 3) * BN;
    const int bm0  = (blockIdx.x >> 2) * BM;
    const size_t aoff = (size_t)(lane & 15) * KDIM + (lane >> 4) * 8;

#define PSTAGE_(TAU, SLOT) do {                                                 \
        int _tc = (TAU);                                                        \
        _Pragma("unroll")                                                       \
        for (int _ab = 0; _ab < 2; ++_ab) {                                     \
            const unsigned short* _b = _ab ? Wp : Ap;                           \
            int _r0 = _ab ? bn0 : bm0;                                          \
            _Pragma("unroll")                                                   \
            for (int _j = 0; _j < 2; ++_j) {                                    \
                int _f = wid * 2 + _j;                                          \
                gload16(_b + (size_t)(_r0 + _f * 16) * KDIM + _tc * BK + aoff,  \
                        &lds[SLOT][_ab][_f][0]);                                \
            }                                                                   \
        }                                                                       \
    } while (0)

    f32x4  acc[8][4];
    f32x16 acc32[4][2];
    if (VARIANT != 3) {
#pragma unroll
        for (int mi = 0; mi < 8; ++mi)
#pragma unroll
            for (int ni = 0; ni < 4; ++ni)
                acc[mi][ni] = (f32x4){0.f, 0.f, 0.f, 0.f};
    } else {
#pragma unroll
        for (int mf = 0; mf < 4; ++mf)
#pragma unroll
            for (int nf = 0; nf < 2; ++nf)
#pragma unroll
                for (int e = 0; e < 16; ++e) acc32[mf][nf][e] = 0.f;
    }

    if (VARIANT != 1) { PSTAGE_(0, 0); PSTAGE_(1, 1); PSTAGE_(2, 2); }
    __builtin_amdgcn_s_barrier();

#pragma unroll 1
    for (int u = 0; u < REPS * NT; ++u) {
        const int slot = u & 3;
        if (VARIANT != 1) PSTAGE_((u + 3) & (NT - 1), (u + 3) & 3);
        if (VARIANT != 1 && VARIANT != 2)
            asm volatile("s_waitcnt vmcnt(12)" ::: "memory");
        __builtin_amdgcn_s_barrier();

        short8 af[8], bq[4];
#pragma unroll
        for (int mi = 0; mi < 8; ++mi)
            af[mi] = *reinterpret_cast<const short8*>(&lds[slot][0][wm * 8 + mi][lane * 8]);
#pragma unroll
        for (int ni = 0; ni < 4; ++ni)
            bq[ni] = *reinterpret_cast<const short8*>(&lds[slot][1][wn * 4 + ni][lane * 8]);

        __builtin_amdgcn_s_setprio(1);
        if (VARIANT != 3) {
#pragma unroll
            for (int mi = 0; mi < 8; ++mi)
#pragma unroll
                for (int ni = 0; ni < 4; ++ni)
                    acc[mi][ni] = __builtin_amdgcn_mfma_f32_16x16x32_bf16(
                        af[mi], bq[ni], acc[mi][ni], 0, 0, 0);
        } else {
            // 16 MFMA of 32x32x16 (layout-garbage, issue/pipe-shape probe)
#pragma unroll
            for (int mf = 0; mf < 4; ++mf)
#pragma unroll
                for (int nf = 0; nf < 2; ++nf)
#pragma unroll
                    for (int ks = 0; ks < 2; ++ks)
                        acc32[mf][nf] = __builtin_amdgcn_mfma_f32_32x32x16_bf16(
                            af[mf * 2 + ks], bq[nf * 2 + ks], acc32[mf][nf], 0, 0, 0);
        }
        __builtin_amdgcn_s_setprio(0);
        __builtin_amdgcn_s_barrier();
    }
    asm volatile("s_waitcnt vmcnt(0)" ::: "memory");
    __builtin_amdgcn_s_barrier();

    float s = 0.f;
    if (VARIANT != 3) {
#pragma unroll
        for (int mi = 0; mi < 8; ++mi)
#pragma unroll
            for (int ni = 0; ni < 4; ++ni)
                s += acc[mi][ni][0] + acc[mi][ni][1] + acc[mi][ni][2] + acc[mi][ni][3];
    } else {
#pragma unroll
        for (int mf = 0; mf < 4; ++mf)
#pragma unroll
            for (int nf = 0; nf < 2; ++nf)
#pragma unroll
                for (int e = 0; e < 16; ++e) s += acc32[mf][nf][e];
    }
    Cout[blockIdx.x * 512 + t] = s;
#undef PSTAGE_
}

// ---------------------------------------------------------------------------
// Per-row attention: K,V now read from fused KV buffer (row stride 2048).
// ---------------------------------------------------------------------------
__global__ __launch_bounds__(256) void attn_k(
    const unsigned short* __restrict__ Qb, const unsigned short* __restrict__ KVb,
    unsigned short* __restrict__ Fb)
{
    __shared__ alignas(16) unsigned short KL[4][1024];
    __shared__ alignas(16) unsigned short VL[4][1024];
    const int t = threadIdx.x;
    const int lane = t & 63;
    const int wid = t >> 6;
    const size_t row = (size_t)blockIdx.x * 4 + wid;
    const size_t base = row * 1024;
    const size_t bkv  = row * 2048;
    const int off = lane * 16;

    ushort8v q0 = *reinterpret_cast<const ushort8v*>(&Qb[base + off]);
    ushort8v q1 = *reinterpret_cast<const ushort8v*>(&Qb[base + off + 8]);
    float qf[16];
#pragma unroll
    for (int j = 0; j < 8; ++j) { qf[j] = bf2f(q0[j]); qf[8 + j] = bf2f(q1[j]); }

    *reinterpret_cast<ushort8v*>(&KL[wid][off])     = *reinterpret_cast<const ushort8v*>(&KVb[bkv + off]);
    *reinterpret_cast<ushort8v*>(&KL[wid][off + 8]) = *reinterpret_cast<const ushort8v*>(&KVb[bkv + off + 8]);
    *reinterpret_cast<ushort8v*>(&VL[wid][off])     = *reinterpret_cast<const ushort8v*>(&KVb[bkv + 1024 + off]);
    *reinterpret_cast<ushort8v*>(&VL[wid][off + 8]) = *reinterpret_cast<const ushort8v*>(&KVb[bkv + 1024 + off + 8]);
    __syncthreads();

    const int sub = lane & 3;
    float s[16];
#pragma unroll
    for (int g = 0; g < 16; ++g) {
        const ushort8v k0 = *reinterpret_cast<const ushort8v*>(&KL[wid][g * 64 + sub * 16]);
        const ushort8v k1 = *reinterpret_cast<const ushort8v*>(&KL[wid][g * 64 + sub * 16 + 8]);
        float acc = 0.f;
#pragma unroll
        for (int j = 0; j < 8; ++j)
            acc += qf[j] * bf2f(k0[j]) + qf[8 + j] * bf2f(k1[j]);
        s[g] = acc;
    }
#pragma unroll
    for (int m = 1; m <= 2; m <<= 1)
#pragma unroll
        for (int g = 0; g < 16; ++g)
            s[g] += __shfl_xor(s[g], m, 64);

    float mx = s[0];
#pragma unroll
    for (int g = 1; g < 16; ++g) mx = fmaxf(mx, s[g]);
    float p[16], denom = 0.f;
#pragma unroll
    for (int g = 0; g < 16; ++g) {
        p[g] = __expf((s[g] - mx) * 0.125f);
        denom += p[g];
    }
    float inv = 1.f / denom;

    float f[16];
#pragma unroll
    for (int j = 0; j < 16; ++j) f[j] = 0.f;
#pragma unroll
    for (int g = 0; g < 16; ++g) {
        float pg = p[g] * inv;
        const ushort8v v0 = *reinterpret_cast<const ushort8v*>(&VL[wid][g * 64 + sub * 16]);
        const ushort8v v1 = *reinterpret_cast<const ushort8v*>(&VL[wid][g * 64 + sub * 16 + 8]);
#pragma unroll
        for (int j = 0; j < 8; ++j) {
            f[j]     += pg * bf2f(v0[j]);
            f[8 + j] += pg * bf2f(v1[j]);
        }
    }
    ushort8v o0, o1;
#pragma unroll
    for (int j = 0; j < 8; ++j) { o0[j] = f2bf(f[j]); o1[j] = f2bf(f[8 + j]); }
    *reinterpret_cast<ushort8v*>(&Fb[base + off])     = o0;
    *reinterpret_cast<ushort8v*>(&Fb[base + off + 8]) = o1;
}

// ---------------------------------------------------------------------------
extern "C" void kernel_launch(void* const* d_in, const int* in_sizes, int n_in,
                              void* d_out, int out_size, void* d_ws, size_t ws_size,
                              hipStream_t stream)
{
    (void)in_sizes; (void)n_in; (void)out_size; (void)ws_size;
    const float* latent = (const float*)d_in[0];
    const float* cond   = (const float*)d_in[1];
    const float* Wq     = (const float*)d_in[2];
    const float* Wk     = (const float*)d_in[3];
    const float* Wv     = (const float*)d_in[4];
    const float* Wout   = (const float*)d_in[5];
    const float* bout   = (const float*)d_in[6];
    float* out = (float*)d_out;

    char* ws = (char*)d_ws;
    const size_t MB = 1ull << 20;
    unsigned short* wqb = (unsigned short*)(ws + 0 * MB);
    unsigned short* wkb = (unsigned short*)(ws + 2 * MB);   // [Wk; Wv] contiguous
    unsigned short* wvb = (unsigned short*)(ws + 4 * MB);
    unsigned short* wob = (unsigned short*)(ws + 6 * MB);
    unsigned short* Qb  = (unsigned short*)(ws + 8 * MB);               // 128 MB
    unsigned short* KVb = (unsigned short*)(ws + 136 * MB);             // 256 MB fused K|V
    unsigned short* Lb  = (unsigned short*)(ws + 392 * MB);             // 128 MB latent bf16
    unsigned short* Cb  = (unsigned short*)(ws + 520 * MB);             // 128 MB cond bf16
    float* probeOut     = (float*)(ws + 520 * MB);                      // reuse Cb (dead post-KV-GEMM)

    const int wn4 = (KDIM * NDIM) / 4;
    f32_to_bf16_k<<<1024, 256, 0, stream>>>(Wq,   wqb, wn4);
    f32_to_bf16_k<<<1024, 256, 0, stream>>>(Wk,   wkb, wn4);
    f32_to_bf16_k<<<1024, 256, 0, stream>>>(Wv,   wvb, wn4);
    f32_to_bf16_k<<<1024, 256, 0, stream>>>(Wout, wob, wn4);

    const int an4 = (NB * KDIM) / 4;
    f32_to_bf16_k<<<4096, 256, 0, stream>>>(latent, Lb, an4);
    f32_to_bf16_k<<<4096, 256, 0, stream>>>(cond,   Cb, an4);

    // Q projection (N=1024) and fused K|V projection (N=2048, W stacked)
    gemm256<0, 1024><<<1024, 512, 0, stream>>>(Lb, wqb, nullptr, Qb);
    gemm256<0, 2048><<<2048, 512, 0, stream>>>(Cb, wkb, nullptr, KVb);

    attn_k<<<NB / 4, 256, 0, stream>>>(Qb, KVb, Qb);

    gemm256<1, 1024><<<1024, 512, 0, stream>>>(Qb, wob, bout, out);

    // ---- diagnostic probes (timing only; scratch output; dead inputs OK) ----
    gemm_probe<0, 6 ><<<256, 512, 0, stream>>>(Lb, wqb, probeOut);  // full (anchor)
    gemm_probe<1, 10><<<256, 512, 0, stream>>>(Lb, wqb, probeOut);  // no-stage
    gemm_probe<2, 8 ><<<256, 512, 0, stream>>>(Lb, wqb, probeOut);  // no-vmcnt-wait
    gemm_probe<3, 12><<<256, 512, 0, stream>>>(Lb, wqb, probeOut);  // 32x32-shaped
}

// Round 11
// 1012.686 us; speedup vs baseline: 2.0840x; 2.0840x over previous
//
#include <hip/hip_runtime.h>
#include <hip/hip_bf16.h>

// Problem constants
#define NB    65536      // batch rows
#define KDIM  1024       // reduction dim for all projections
#define NDIM  1024       // output dim per projection

// 256x256 GEMM geometry, BK=32, quad-buffered ring (depth-3 prefetch)
#define BM 256
#define BN 256
#define BK 32
#define NT (KDIM / BK)   // 32 K-tiles

typedef float f32x4  __attribute__((ext_vector_type(4)));
typedef short short8 __attribute__((ext_vector_type(8)));
typedef unsigned short ushort8v __attribute__((ext_vector_type(8)));

static __device__ __forceinline__ unsigned short f2bf(float f) {
    union { float f; unsigned u; } v; v.f = f;
    unsigned r = v.u + 0x7FFFu + ((v.u >> 16) & 1u);
    return (unsigned short)(r >> 16);
}
static __device__ __forceinline__ float bf2f(unsigned short h) {
    union { unsigned u; float f; } v; v.u = ((unsigned)h) << 16;
    return v.f;
}

// async global->LDS, 16B per lane. LDS dest = wave-uniform base + lane*16.
static __device__ __forceinline__ void gload16(const unsigned short* g, unsigned short* l) {
    __builtin_amdgcn_global_load_lds(
        (const __attribute__((address_space(1))) unsigned int*)g,
        (__attribute__((address_space(3))) unsigned int*)l, 16, 0, 0);
}

// ---------------------------------------------------------------------------
// PACKED LAYOUT (GEMM-consumption order; r10 probe: cold 64B-scatter fetch
// caps at 1.98 TB/s and the GEMM main loop = FETCH/1.98TB/s exactly):
//   1KB chunk index = ((r>>8)*32 + t)*16 + ((r>>4)&15)
//   inner (shorts)  = kc*128 + (r&15)*8 + pos,  col c = t*32 + kc*8 + pos
// A wave's gload16 of one chunk (lane*16B) is CONTIGUOUS -> streaming fetch.
// LDS image after gload16 == old fragment-ordered layout (ds_reads unchanged).
// ---------------------------------------------------------------------------

// fp32 row-major [nrows][1024] -> packed bf16. One 16-row f-stripe per block.
// Reads contiguous 256B/thread; block writes every touched 1KB chunk fully
// (no cross-block partial lines).
__global__ __launch_bounds__(256) void pack_f32_k(
    const float* __restrict__ src, unsigned short* __restrict__ dst)
{
    const int tid = threadIdx.x;
    const int r   = blockIdx.x * 16 + (tid >> 4);   // global row
    const int cb  = (tid & 15) * 64;                // 64 cols per thread
    const int p   = r >> 8;
    const int f   = (r >> 4) & 15;
    const int rl  = r & 15;
    const float* s = src + (size_t)r * 1024 + cb;
#pragma unroll
    for (int g = 0; g < 8; ++g) {
        float4 va = *reinterpret_cast<const float4*>(s + g * 8);
        float4 vb = *reinterpret_cast<const float4*>(s + g * 8 + 4);
        ushort8v o;
        o[0] = f2bf(va.x); o[1] = f2bf(va.y); o[2] = f2bf(va.z); o[3] = f2bf(va.w);
        o[4] = f2bf(vb.x); o[5] = f2bf(vb.y); o[6] = f2bf(vb.z); o[7] = f2bf(vb.w);
        const int c0 = cb + g * 8;
        const int t  = c0 >> 5;
        const int kc = (c0 & 31) >> 3;
        *reinterpret_cast<ushort8v*>(
            &dst[((size_t)(p * 32 + t) * 16 + f) * 512 + kc * 128 + rl * 8]) = o;
    }
}

// ---------------------------------------------------------------------------
// 256x256 GEMM, BK=32, ring-4 LDS depth-3 prefetch (r8 structure) on PACKED
// operands: every stage fetch is 16KB contiguous per tile per side.
// Templated on output width NN (1024 single-proj / 2048 fused K|V).
// ---------------------------------------------------------------------------
template<int OUT_F32, int NN>
__global__ __launch_bounds__(512, 2) void gemm256(
    const unsigned short* __restrict__ Ap, const unsigned short* __restrict__ Wp,
    const float* __restrict__ bias, void* __restrict__ Cptr)
{
    constexpr int GN = NN / BN;              // 4 or 8 col tiles
    __shared__ alignas(16) unsigned short lds[4][2][16][512];

    const int t    = threadIdx.x;
    const int lane = t & 63;
    const int wid  = t >> 6;                 // 0..7
    const int wm   = wid >> 2;               // 0..1  (128 rows each)
    const int wn   = wid & 3;                // 0..3  (64 cols each)

    // XCD-chunked swizzle (nwg % 8 == 0): same-panel blocks share one L2
    const int nwg  = gridDim.x;
    const int cpx  = nwg >> 3;
    const int orig = blockIdx.x;
    const int wgid = (orig & 7) * cpx + (orig >> 3);
    const int bn0  = (wgid & (GN - 1)) * BN;
    const int bm0  = (wgid / GN) * BM;

    const int pA = bm0 >> 8;                 // A panel index
    const int pB = bn0 >> 8;                 // W panel index

#define STAGE_(TAU, SLOT) do {                                                  \
        int _tc = (TAU) < NT ? (TAU) : NT - 1;                                  \
        _Pragma("unroll")                                                       \
        for (int _ab = 0; _ab < 2; ++_ab) {                                     \
            const unsigned short* _b = _ab ? Wp : Ap;                           \
            int _pp = _ab ? pB : pA;                                            \
            _Pragma("unroll")                                                   \
            for (int _j = 0; _j < 2; ++_j) {                                    \
                int _f = wid * 2 + _j;                                          \
                gload16(_b + ((size_t)(_pp * 32 + _tc) * 16 + _f) * 512 + lane * 8, \
                        &lds[SLOT][_ab][_f][0]);                                \
            }                                                                   \
        }                                                                       \
    } while (0)

    f32x4 acc[8][4];
#pragma unroll
    for (int mi = 0; mi < 8; ++mi)
#pragma unroll
        for (int ni = 0; ni < 4; ++ni)
            acc[mi][ni] = (f32x4){0.f, 0.f, 0.f, 0.f};

    STAGE_(0, 0); STAGE_(1, 1); STAGE_(2, 2);

#pragma unroll 1
    for (int tt = 0; tt < NT; ++tt) {
        const int slot = tt & 3;
        STAGE_(tt + 3, (tt + 3) & 3);
        asm volatile("s_waitcnt vmcnt(12)" ::: "memory");  // stage(tt) landed
        __builtin_amdgcn_s_barrier();

        short8 af[8], bq[4];
#pragma unroll
        for (int mi = 0; mi < 8; ++mi)
            af[mi] = *reinterpret_cast<const short8*>(&lds[slot][0][wm * 8 + mi][lane * 8]);
#pragma unroll
        for (int ni = 0; ni < 4; ++ni)
            bq[ni] = *reinterpret_cast<const short8*>(&lds[slot][1][wn * 4 + ni][lane * 8]);
        __builtin_amdgcn_s_setprio(1);
#pragma unroll
        for (int mi = 0; mi < 8; ++mi)
#pragma unroll
            for (int ni = 0; ni < 4; ++ni)
                acc[mi][ni] = __builtin_amdgcn_mfma_f32_16x16x32_bf16(
                    af[mi], bq[ni], acc[mi][ni], 0, 0, 0);
        __builtin_amdgcn_s_setprio(0);
        __builtin_amdgcn_s_barrier();
    }
    asm volatile("s_waitcnt vmcnt(0)" ::: "memory");
    __builtin_amdgcn_s_barrier();

    // epilogue: LDS bounce -> full-line stores (WRITE_SIZE exact-ideal, r7+)
    const int crow = (lane >> 4) * 4;
    const int ccol = lane & 15;
    if (OUT_F32) {
        float* Cf = (float*)Cptr;
        float* bbf = reinterpret_cast<float*>(&lds[0][0][0][0]);
        float bv[4];
#pragma unroll
        for (int ni = 0; ni < 4; ++ni)
            bv[ni] = bias[bn0 + wn * 64 + ni * 16 + ccol];
#pragma unroll
        for (int p = 0; p < 4; ++p) {
            if (wm == (p >> 1)) {
#pragma unroll
                for (int ml = 0; ml < 4; ++ml)
#pragma unroll
                    for (int ni = 0; ni < 4; ++ni)
#pragma unroll
                        for (int r = 0; r < 4; ++r)
                            bbf[(ml * 16 + crow + r) * 268 + wn * 64 + ni * 16 + ccol]
                                = acc[(p & 1) * 4 + ml][ni][r] + bv[ni];
            }
            __syncthreads();
#pragma unroll
            for (int it = 0; it < 8; ++it) {
                int lrow = wid * 8 + it;
                f32x4 v = *reinterpret_cast<const f32x4*>(&bbf[lrow * 268 + lane * 4]);
                *reinterpret_cast<f32x4*>(
                    &Cf[(size_t)(bm0 + p * 64 + lrow) * NN + bn0 + lane * 4]) = v;
            }
            __syncthreads();
        }
    } else {
        unsigned short* Cb = (unsigned short*)Cptr;
        unsigned short* bb = &lds[0][0][0][0];
#pragma unroll
        for (int p = 0; p < 2; ++p) {
            if (wm == p) {
#pragma unroll
                for (int ml = 0; ml < 8; ++ml)
#pragma unroll
                    for (int ni = 0; ni < 4; ++ni)
#pragma unroll
                        for (int r = 0; r < 4; ++r)
                            bb[(ml * 16 + crow + r) * 264 + wn * 64 + ni * 16 + ccol]
                                = f2bf(acc[ml][ni][r]);
            }
            __syncthreads();
#pragma unroll
            for (int it = 0; it < 8; ++it) {
                int lrow = wid * 16 + it * 2 + (lane >> 5);
                int lcol = (lane & 31) * 8;
                ushort8v v = *reinterpret_cast<const ushort8v*>(&bb[lrow * 264 + lcol]);
                *reinterpret_cast<ushort8v*>(
                    &Cb[(size_t)(bm0 + p * 128 + lrow) * NN + bn0 + lcol]) = v;
            }
            __syncthreads();
        }
    }
#undef STAGE_
}

// ---------------------------------------------------------------------------
// Per-row attention, 16 rows/block (16 waves), wave-per-row body unchanged.
// Reads Q (row-major) + fused KV (row stride 2048); writes feats PACKED via
// LDS bounce (block = one 16-row f-stripe -> every 1KB chunk fully written).
// ---------------------------------------------------------------------------
__global__ __launch_bounds__(1024) void attn_k(
    const unsigned short* __restrict__ Qb, const unsigned short* __restrict__ KVb,
    unsigned short* __restrict__ Fp)
{
    __shared__ alignas(16) unsigned short KL[16][1024];   // K rows; reused as feats
    __shared__ alignas(16) unsigned short VL[16][1024];
    const int t = threadIdx.x;
    const int lane = t & 63;
    const int wid = t >> 6;                       // 0..15
    const size_t row = (size_t)blockIdx.x * 16 + wid;
    const size_t base = row * 1024;
    const size_t bkv  = row * 2048;
    const int off = lane * 16;

    ushort8v q0 = *reinterpret_cast<const ushort8v*>(&Qb[base + off]);
    ushort8v q1 = *reinterpret_cast<const ushort8v*>(&Qb[base + off + 8]);
    float qf[16];
#pragma unroll
    for (int j = 0; j < 8; ++j) { qf[j] = bf2f(q0[j]); qf[8 + j] = bf2f(q1[j]); }

    *reinterpret_cast<ushort8v*>(&KL[wid][off])     = *reinterpret_cast<const ushort8v*>(&KVb[bkv + off]);
    *reinterpret_cast<ushort8v*>(&KL[wid][off + 8]) = *reinterpret_cast<const ushort8v*>(&KVb[bkv + off + 8]);
    *reinterpret_cast<ushort8v*>(&VL[wid][off])     = *reinterpret_cast<const ushort8v*>(&KVb[bkv + 1024 + off]);
    *reinterpret_cast<ushort8v*>(&VL[wid][off + 8]) = *reinterpret_cast<const ushort8v*>(&KVb[bkv + 1024 + off + 8]);
    __syncthreads();

    const int sub = lane & 3;
    float s[16];
#pragma unroll
    for (int g = 0; g < 16; ++g) {
        const ushort8v k0 = *reinterpret_cast<const ushort8v*>(&KL[wid][g * 64 + sub * 16]);
        const ushort8v k1 = *reinterpret_cast<const ushort8v*>(&KL[wid][g * 64 + sub * 16 + 8]);
        float acc = 0.f;
#pragma unroll
        for (int j = 0; j < 8; ++j)
            acc += qf[j] * bf2f(k0[j]) + qf[8 + j] * bf2f(k1[j]);
        s[g] = acc;
    }
#pragma unroll
    for (int m = 1; m <= 2; m <<= 1)
#pragma unroll
        for (int g = 0; g < 16; ++g)
            s[g] += __shfl_xor(s[g], m, 64);

    float mx = s[0];
#pragma unroll
    for (int g = 1; g < 16; ++g) mx = fmaxf(mx, s[g]);
    float p[16], denom = 0.f;
#pragma unroll
    for (int g = 0; g < 16; ++g) {
        p[g] = __expf((s[g] - mx) * 0.125f);
        denom += p[g];
    }
    float inv = 1.f / denom;

    float f[16];
#pragma unroll
    for (int j = 0; j < 16; ++j) f[j] = 0.f;
#pragma unroll
    for (int g = 0; g < 16; ++g) {
        float pg = p[g] * inv;
        const ushort8v v0 = *reinterpret_cast<const ushort8v*>(&VL[wid][g * 64 + sub * 16]);
        const ushort8v v1 = *reinterpret_cast<const ushort8v*>(&VL[wid][g * 64 + sub * 16 + 8]);
#pragma unroll
        for (int j = 0; j < 8; ++j) {
            f[j]     += pg * bf2f(v0[j]);
            f[8 + j] += pg * bf2f(v1[j]);
        }
    }
    ushort8v o0, o1;
#pragma unroll
    for (int j = 0; j < 8; ++j) { o0[j] = f2bf(f[j]); o1[j] = f2bf(f[8 + j]); }
    // stash row into FL (= KL; own-wave region, own reads long done)
    *reinterpret_cast<ushort8v*>(&KL[wid][off])     = o0;
    *reinterpret_cast<ushort8v*>(&KL[wid][off + 8]) = o1;
    __syncthreads();

    // cooperative packed write: block = f-stripe (p, f); 32KB total
    const int r0 = blockIdx.x * 16;
    const int pp = r0 >> 8;
    const int ff = (r0 >> 4) & 15;
    const int tt = t >> 5;          // tile 0..31
    const int kc = (t >> 3) & 3;    // k-chunk 0..3
    const int rp = t & 7;           // row pair 0..7
    unsigned short* db = &Fp[((size_t)(pp * 32 + tt) * 16 + ff) * 512 + kc * 128 + rp * 16];
    *reinterpret_cast<ushort8v*>(db)     = *reinterpret_cast<const ushort8v*>(&KL[rp * 2][tt * 32 + kc * 8]);
    *reinterpret_cast<ushort8v*>(db + 8) = *reinterpret_cast<const ushort8v*>(&KL[rp * 2 + 1][tt * 32 + kc * 8]);
}

// ---------------------------------------------------------------------------
extern "C" void kernel_launch(void* const* d_in, const int* in_sizes, int n_in,
                              void* d_out, int out_size, void* d_ws, size_t ws_size,
                              hipStream_t stream)
{
    (void)in_sizes; (void)n_in; (void)out_size; (void)ws_size;
    const float* latent = (const float*)d_in[0];
    const float* cond   = (const float*)d_in[1];
    const float* Wq     = (const float*)d_in[2];
    const float* Wk     = (const float*)d_in[3];
    const float* Wv     = (const float*)d_in[4];
    const float* Wout   = (const float*)d_in[5];
    const float* bout   = (const float*)d_in[6];
    float* out = (float*)d_out;

    char* ws = (char*)d_ws;
    const size_t MB = 1ull << 20;
    unsigned short* wqp  = (unsigned short*)(ws + 0 * MB);    // 2 MB packed Wq
    unsigned short* wkvp = (unsigned short*)(ws + 2 * MB);    // 4 MB packed [Wk;Wv]
    unsigned short* wop  = (unsigned short*)(ws + 6 * MB);    // 2 MB packed Wout
    unsigned short* Qb   = (unsigned short*)(ws + 8 * MB);    // 128 MB row-major Q
    unsigned short* KVb  = (unsigned short*)(ws + 136 * MB);  // 256 MB row-major fused K|V
    unsigned short* Lp   = (unsigned short*)(ws + 392 * MB);  // 128 MB packed latent; reused as packed feats
    unsigned short* Cp   = (unsigned short*)(ws + 520 * MB);  // 128 MB packed cond
    unsigned short* Fp   = Lp;                                // Lp dead after GEMM-Q

    // weight packs (tiny)
    pack_f32_k<<<NDIM / 16, 256, 0, stream>>>(Wq,   wqp);
    pack_f32_k<<<NDIM / 16, 256, 0, stream>>>(Wk,   wkvp);
    pack_f32_k<<<NDIM / 16, 256, 0, stream>>>(Wv,   wkvp + 1048576);  // panels 4..7
    pack_f32_k<<<NDIM / 16, 256, 0, stream>>>(Wout, wop);

    // activation packs (fp32 -> packed bf16)
    pack_f32_k<<<NB / 16, 256, 0, stream>>>(latent, Lp);
    pack_f32_k<<<NB / 16, 256, 0, stream>>>(cond,   Cp);

    // Q projection (N=1024) and fused K|V projection (N=2048, W stacked)
    gemm256<0, 1024><<<1024, 512, 0, stream>>>(Lp, wqp,  nullptr, Qb);
    gemm256<0, 2048><<<2048, 512, 0, stream>>>(Cp, wkvp, nullptr, KVb);

    // attention: row-major Q/KV in, PACKED feats out (into Fp = Lp)
    attn_k<<<NB / 16, 1024, 0, stream>>>(Qb, KVb, Fp);

    // output projection reads packed feats
    gemm256<1, 1024><<<1024, 512, 0, stream>>>(Fp, wop, bout, out);
}

// Round 12
// 1005.303 us; speedup vs baseline: 2.0993x; 1.0073x over previous
//
#include <hip/hip_runtime.h>
#include <hip/hip_bf16.h>

// Problem constants
#define NB    65536      // batch rows
#define KDIM  1024       // reduction dim for all projections
#define NDIM  1024       // output dim per projection

// 256x256 GEMM geometry, BK=32, quad-buffered ring (depth-3 prefetch)
#define BM 256
#define BN 256
#define BK 32
#define NT (KDIM / BK)   // 32 K-tiles

typedef float f32x4  __attribute__((ext_vector_type(4)));
typedef short short8 __attribute__((ext_vector_type(8)));
typedef unsigned short ushort8v __attribute__((ext_vector_type(8)));

static __device__ __forceinline__ unsigned short f2bf(float f) {
    union { float f; unsigned u; } v; v.f = f;
    unsigned r = v.u + 0x7FFFu + ((v.u >> 16) & 1u);
    return (unsigned short)(r >> 16);
}
static __device__ __forceinline__ float bf2f(unsigned short h) {
    union { unsigned u; float f; } v; v.u = ((unsigned)h) << 16;
    return v.f;
}

// async global->LDS, 16B per lane. LDS dest = wave-uniform base + lane*16.
static __device__ __forceinline__ void gload16(const unsigned short* g, unsigned short* l) {
    __builtin_amdgcn_global_load_lds(
        (const __attribute__((address_space(1))) unsigned int*)g,
        (__attribute__((address_space(3))) unsigned int*)l, 16, 0, 0);
}

// ---------------------------------------------------------------------------
// PACKED LAYOUT (GEMM-consumption order; r10 probe: cold 64B-scatter fetch
// caps at 1.98 TB/s; r11: packing -> 900 TF, FETCH 1.5x ideal, streaming):
//   1KB chunk index = ((r>>8)*32 + t)*16 + ((r>>4)&15)
//   inner (shorts)  = kc*128 + (r&15)*8 + pos,  col c = t*32 + kc*8 + pos
// ---------------------------------------------------------------------------

// fp32 row-major [nrows][1024] -> packed bf16. One 16-row f-stripe per block.
__global__ __launch_bounds__(256) void pack_f32_k(
    const float* __restrict__ src, unsigned short* __restrict__ dst)
{
    const int tid = threadIdx.x;
    const int r   = blockIdx.x * 16 + (tid >> 4);   // global row
    const int cb  = (tid & 15) * 64;                // 64 cols per thread
    const int p   = r >> 8;
    const int f   = (r >> 4) & 15;
    const int rl  = r & 15;
    const float* s = src + (size_t)r * 1024 + cb;
#pragma unroll
    for (int g = 0; g < 8; ++g) {
        float4 va = *reinterpret_cast<const float4*>(s + g * 8);
        float4 vb = *reinterpret_cast<const float4*>(s + g * 8 + 4);
        ushort8v o;
        o[0] = f2bf(va.x); o[1] = f2bf(va.y); o[2] = f2bf(va.z); o[3] = f2bf(va.w);
        o[4] = f2bf(vb.x); o[5] = f2bf(vb.y); o[6] = f2bf(vb.z); o[7] = f2bf(vb.w);
        const int c0 = cb + g * 8;
        const int t  = c0 >> 5;
        const int kc = (c0 & 31) >> 3;
        *reinterpret_cast<ushort8v*>(
            &dst[((size_t)(p * 32 + t) * 16 + f) * 512 + kc * 128 + rl * 8]) = o;
    }
}

// ---------------------------------------------------------------------------
// 256x256 GEMM, BK=32, ring-4 LDS, PACKED operands, m201 PHASE CADENCE:
// per K-tile 2 phases of 16 MFMA:
//  p1: {8 ds_reads (af-lo + bq) | stage A-half(t+3); bar; lgkm0; MFMA-lo; bar}
//  p2: {4 ds_reads (af-hi)      | stage B-half(t+3); vmcnt(8); bar; lgkm0;
//       MFMA-hi; bar}
// Counted vmcnt(8) once per tile, never drains in-loop (derivation: after
// issuing U(t+3,B), units newer than tile t+1's last = 4 x 2 loads = 8;
// vmcnt(8) validates tile t+1 for the next iteration's reads). Prologue
// stages tiles 0,1,2 then vmcnt(8) validates tile 0. Overwrite of slot t&3
// (by U(t+4,A), issued in tile t+1 p1) is >=1 barrier after tile t's reads
// completed (lgkm-before-MFMA precedes p2's trailing barrier). Tail clamps
// re-stage tile NT-1 into dead slots (cadence-preserving, race-free).
// r5-r9 phase experiments were fetch-bound (rule #23 regime mismatch,
// proven by r10 probe); this is the first phase test in the right regime.
// ---------------------------------------------------------------------------
template<int OUT_F32, int NN>
__global__ __launch_bounds__(512, 2) void gemm256(
    const unsigned short* __restrict__ Ap, const unsigned short* __restrict__ Wp,
    const float* __restrict__ bias, void* __restrict__ Cptr)
{
    constexpr int GN = NN / BN;              // 4 or 8 col tiles
    __shared__ alignas(16) unsigned short lds[4][2][16][512];

    const int t    = threadIdx.x;
    const int lane = t & 63;
    const int wid  = t >> 6;                 // 0..7
    const int wm   = wid >> 2;               // 0..1  (128 rows each)
    const int wn   = wid & 3;                // 0..3  (64 cols each)

    // XCD-chunked swizzle (nwg % 8 == 0): same-panel blocks share one L2
    const int nwg  = gridDim.x;
    const int cpx  = nwg >> 3;
    const int orig = blockIdx.x;
    const int wgid = (orig & 7) * cpx + (orig >> 3);
    const int bn0  = (wgid & (GN - 1)) * BN;
    const int bm0  = (wgid / GN) * BM;

    const int pA = bm0 >> 8;                 // A panel index
    const int pB = bn0 >> 8;                 // W panel index

    // stage ONE side (AB: 0=A,1=B) of K-tile TAU into ring slot SLOT (2 gloads)
#define STAGE1_(TAU, SLOT, AB) do {                                             \
        int _tc = (TAU) < NT ? (TAU) : NT - 1;                                  \
        const unsigned short* _b = (AB) ? Wp : Ap;                              \
        int _pp = (AB) ? pB : pA;                                               \
        _Pragma("unroll")                                                       \
        for (int _j = 0; _j < 2; ++_j) {                                        \
            int _f = wid * 2 + _j;                                              \
            gload16(_b + ((size_t)(_pp * 32 + _tc) * 16 + _f) * 512 + lane * 8, \
                    &lds[SLOT][AB][_f][0]);                                     \
        }                                                                       \
    } while (0)

#define LDA_(S, MI) \
    (*reinterpret_cast<const short8*>(&lds[S][0][wm * 8 + (MI)][lane * 8]))
#define LDB_(S, NI) \
    (*reinterpret_cast<const short8*>(&lds[S][1][wn * 4 + (NI)][lane * 8]))

    f32x4 acc[8][4];
#pragma unroll
    for (int mi = 0; mi < 8; ++mi)
#pragma unroll
        for (int ni = 0; ni < 4; ++ni)
            acc[mi][ni] = (f32x4){0.f, 0.f, 0.f, 0.f};

    // prologue: stage tiles 0,1,2 (12 loads); validate tile 0 (vmcnt(8))
    STAGE1_(0, 0, 0); STAGE1_(0, 0, 1);
    STAGE1_(1, 1, 0); STAGE1_(1, 1, 1);
    STAGE1_(2, 2, 0); STAGE1_(2, 2, 1);
    asm volatile("s_waitcnt vmcnt(8)" ::: "memory");
    __builtin_amdgcn_s_barrier();

#pragma unroll 1
    for (int tt = 0; tt < NT; ++tt) {
        const int slot = tt & 3;
        short8 af0[4], af1[4], bq[4];

        // ---- phase 1: af-lo + bq reads | stage A(t+3) | MFMA mi 0-3 ----
#pragma unroll
        for (int mi = 0; mi < 4; ++mi) af0[mi] = LDA_(slot, mi);
#pragma unroll
        for (int ni = 0; ni < 4; ++ni) bq[ni] = LDB_(slot, ni);
        STAGE1_(tt + 3, (tt + 3) & 3, 0);
        __builtin_amdgcn_s_barrier();
        asm volatile("s_waitcnt lgkmcnt(0)" ::: "memory");
        __builtin_amdgcn_s_setprio(1);
#pragma unroll
        for (int mi = 0; mi < 4; ++mi)
#pragma unroll
            for (int ni = 0; ni < 4; ++ni)
                acc[mi][ni] = __builtin_amdgcn_mfma_f32_16x16x32_bf16(
                    af0[mi], bq[ni], acc[mi][ni], 0, 0, 0);
        __builtin_amdgcn_s_setprio(0);
        __builtin_amdgcn_s_barrier();

        // ---- phase 2: af-hi reads | stage B(t+3) | vmcnt(8) | MFMA mi 4-7 --
#pragma unroll
        for (int mi = 0; mi < 4; ++mi) af1[mi] = LDA_(slot, 4 + mi);
        STAGE1_(tt + 3, (tt + 3) & 3, 1);
        asm volatile("s_waitcnt vmcnt(8)" ::: "memory");  // tile tt+1 landed
        __builtin_amdgcn_s_barrier();
        asm volatile("s_waitcnt lgkmcnt(0)" ::: "memory");
        __builtin_amdgcn_s_setprio(1);
#pragma unroll
        for (int mi = 0; mi < 4; ++mi)
#pragma unroll
            for (int ni = 0; ni < 4; ++ni)
                acc[4 + mi][ni] = __builtin_amdgcn_mfma_f32_16x16x32_bf16(
                    af1[mi], bq[ni], acc[4 + mi][ni], 0, 0, 0);
        __builtin_amdgcn_s_setprio(0);
        __builtin_amdgcn_s_barrier();
    }
    asm volatile("s_waitcnt vmcnt(0)" ::: "memory");
    __builtin_amdgcn_s_barrier();

    // epilogue: LDS bounce -> full-line stores (WRITE_SIZE exact-ideal, r7+)
    const int crow = (lane >> 4) * 4;
    const int ccol = lane & 15;
    if (OUT_F32) {
        float* Cf = (float*)Cptr;
        float* bbf = reinterpret_cast<float*>(&lds[0][0][0][0]);
        float bv[4];
#pragma unroll
        for (int ni = 0; ni < 4; ++ni)
            bv[ni] = bias[bn0 + wn * 64 + ni * 16 + ccol];
#pragma unroll
        for (int p = 0; p < 4; ++p) {
            if (wm == (p >> 1)) {
#pragma unroll
                for (int ml = 0; ml < 4; ++ml)
#pragma unroll
                    for (int ni = 0; ni < 4; ++ni)
#pragma unroll
                        for (int r = 0; r < 4; ++r)
                            bbf[(ml * 16 + crow + r) * 268 + wn * 64 + ni * 16 + ccol]
                                = acc[(p & 1) * 4 + ml][ni][r] + bv[ni];
            }
            __syncthreads();
#pragma unroll
            for (int it = 0; it < 8; ++it) {
                int lrow = wid * 8 + it;
                f32x4 v = *reinterpret_cast<const f32x4*>(&bbf[lrow * 268 + lane * 4]);
                *reinterpret_cast<f32x4*>(
                    &Cf[(size_t)(bm0 + p * 64 + lrow) * NN + bn0 + lane * 4]) = v;
            }
            __syncthreads();
        }
    } else {
        unsigned short* Cb = (unsigned short*)Cptr;
        unsigned short* bb = &lds[0][0][0][0];
#pragma unroll
        for (int p = 0; p < 2; ++p) {
            if (wm == p) {
#pragma unroll
                for (int ml = 0; ml < 8; ++ml)
#pragma unroll
                    for (int ni = 0; ni < 4; ++ni)
#pragma unroll
                        for (int r = 0; r < 4; ++r)
                            bb[(ml * 16 + crow + r) * 264 + wn * 64 + ni * 16 + ccol]
                                = f2bf(acc[ml][ni][r]);
            }
            __syncthreads();
#pragma unroll
            for (int it = 0; it < 8; ++it) {
                int lrow = wid * 16 + it * 2 + (lane >> 5);
                int lcol = (lane & 31) * 8;
                ushort8v v = *reinterpret_cast<const ushort8v*>(&bb[lrow * 264 + lcol]);
                *reinterpret_cast<ushort8v*>(
                    &Cb[(size_t)(bm0 + p * 128 + lrow) * NN + bn0 + lcol]) = v;
            }
            __syncthreads();
        }
    }
#undef STAGE1_
#undef LDA_
#undef LDB_
}

// ---------------------------------------------------------------------------
// Per-row attention, 16 rows/block (16 waves), wave-per-row body unchanged.
// Reads Q (row-major) + fused KV (row stride 2048); writes feats PACKED via
// LDS bounce (block = one 16-row f-stripe -> every 1KB chunk fully written).
// ---------------------------------------------------------------------------
__global__ __launch_bounds__(1024) void attn_k(
    const unsigned short* __restrict__ Qb, const unsigned short* __restrict__ KVb,
    unsigned short* __restrict__ Fp)
{
    __shared__ alignas(16) unsigned short KL[16][1024];   // K rows; reused as feats
    __shared__ alignas(16) unsigned short VL[16][1024];
    const int t = threadIdx.x;
    const int lane = t & 63;
    const int wid = t >> 6;                       // 0..15
    const size_t row = (size_t)blockIdx.x * 16 + wid;
    const size_t base = row * 1024;
    const size_t bkv  = row * 2048;
    const int off = lane * 16;

    ushort8v q0 = *reinterpret_cast<const ushort8v*>(&Qb[base + off]);
    ushort8v q1 = *reinterpret_cast<const ushort8v*>(&Qb[base + off + 8]);
    float qf[16];
#pragma unroll
    for (int j = 0; j < 8; ++j) { qf[j] = bf2f(q0[j]); qf[8 + j] = bf2f(q1[j]); }

    *reinterpret_cast<ushort8v*>(&KL[wid][off])     = *reinterpret_cast<const ushort8v*>(&KVb[bkv + off]);
    *reinterpret_cast<ushort8v*>(&KL[wid][off + 8]) = *reinterpret_cast<const ushort8v*>(&KVb[bkv + off + 8]);
    *reinterpret_cast<ushort8v*>(&VL[wid][off])     = *reinterpret_cast<const ushort8v*>(&KVb[bkv + 1024 + off]);
    *reinterpret_cast<ushort8v*>(&VL[wid][off + 8]) = *reinterpret_cast<const ushort8v*>(&KVb[bkv + 1024 + off + 8]);
    __syncthreads();

    const int sub = lane & 3;
    float s[16];
#pragma unroll
    for (int g = 0; g < 16; ++g) {
        const ushort8v k0 = *reinterpret_cast<const ushort8v*>(&KL[wid][g * 64 + sub * 16]);
        const ushort8v k1 = *reinterpret_cast<const ushort8v*>(&KL[wid][g * 64 + sub * 16 + 8]);
        float acc = 0.f;
#pragma unroll
        for (int j = 0; j < 8; ++j)
            acc += qf[j] * bf2f(k0[j]) + qf[8 + j] * bf2f(k1[j]);
        s[g] = acc;
    }
#pragma unroll
    for (int m = 1; m <= 2; m <<= 1)
#pragma unroll
        for (int g = 0; g < 16; ++g)
            s[g] += __shfl_xor(s[g], m, 64);

    float mx = s[0];
#pragma unroll
    for (int g = 1; g < 16; ++g) mx = fmaxf(mx, s[g]);
    float p[16], denom = 0.f;
#pragma unroll
    for (int g = 0; g < 16; ++g) {
        p[g] = __expf((s[g] - mx) * 0.125f);
        denom += p[g];
    }
    float inv = 1.f / denom;

    float f[16];
#pragma unroll
    for (int j = 0; j < 16; ++j) f[j] = 0.f;
#pragma unroll
    for (int g = 0; g < 16; ++g) {
        float pg = p[g] * inv;
        const ushort8v v0 = *reinterpret_cast<const ushort8v*>(&VL[wid][g * 64 + sub * 16]);
        const ushort8v v1 = *reinterpret_cast<const ushort8v*>(&VL[wid][g * 64 + sub * 16 + 8]);
#pragma unroll
        for (int j = 0; j < 8; ++j) {
            f[j]     += pg * bf2f(v0[j]);
            f[8 + j] += pg * bf2f(v1[j]);
        }
    }
    ushort8v o0, o1;
#pragma unroll
    for (int j = 0; j < 8; ++j) { o0[j] = f2bf(f[j]); o1[j] = f2bf(f[8 + j]); }
    // stash row into FL (= KL; own-wave region, own reads long done)
    *reinterpret_cast<ushort8v*>(&KL[wid][off])     = o0;
    *reinterpret_cast<ushort8v*>(&KL[wid][off + 8]) = o1;
    __syncthreads();

    // cooperative packed write: block = f-stripe (p, f); 32KB total
    const int r0 = blockIdx.x * 16;
    const int pp = r0 >> 8;
    const int ff = (r0 >> 4) & 15;
    const int tt = t >> 5;          // tile 0..31
    const int kc = (t >> 3) & 3;    // k-chunk 0..3
    const int rp = t & 7;           // row pair 0..7
    unsigned short* db = &Fp[((size_t)(pp * 32 + tt) * 16 + ff) * 512 + kc * 128 + rp * 16];
    *reinterpret_cast<ushort8v*>(db)     = *reinterpret_cast<const ushort8v*>(&KL[rp * 2][tt * 32 + kc * 8]);
    *reinterpret_cast<ushort8v*>(db + 8) = *reinterpret_cast<const ushort8v*>(&KL[rp * 2 + 1][tt * 32 + kc * 8]);
}

// ---------------------------------------------------------------------------
extern "C" void kernel_launch(void* const* d_in, const int* in_sizes, int n_in,
                              void* d_out, int out_size, void* d_ws, size_t ws_size,
                              hipStream_t stream)
{
    (void)in_sizes; (void)n_in; (void)out_size; (void)ws_size;
    const float* latent = (const float*)d_in[0];
    const float* cond   = (const float*)d_in[1];
    const float* Wq     = (const float*)d_in[2];
    const float* Wk     = (const float*)d_in[3];
    const float* Wv     = (const float*)d_in[4];
    const float* Wout   = (const float*)d_in[5];
    const float* bout   = (const float*)d_in[6];
    float* out = (float*)d_out;

    char* ws = (char*)d_ws;
    const size_t MB = 1ull << 20;
    unsigned short* wqp  = (unsigned short*)(ws + 0 * MB);    // 2 MB packed Wq
    unsigned short* wkvp = (unsigned short*)(ws + 2 * MB);    // 4 MB packed [Wk;Wv]
    unsigned short* wop  = (unsigned short*)(ws + 6 * MB);    // 2 MB packed Wout
    unsigned short* Qb   = (unsigned short*)(ws + 8 * MB);    // 128 MB row-major Q
    unsigned short* KVb  = (unsigned short*)(ws + 136 * MB);  // 256 MB row-major fused K|V
    unsigned short* Lp   = (unsigned short*)(ws + 392 * MB);  // 128 MB packed latent; reused as packed feats
    unsigned short* Cp   = (unsigned short*)(ws + 520 * MB);  // 128 MB packed cond
    unsigned short* Fp   = Lp;                                // Lp dead after GEMM-Q

    // weight packs (tiny)
    pack_f32_k<<<NDIM / 16, 256, 0, stream>>>(Wq,   wqp);
    pack_f32_k<<<NDIM / 16, 256, 0, stream>>>(Wk,   wkvp);
    pack_f32_k<<<NDIM / 16, 256, 0, stream>>>(Wv,   wkvp + 1048576);  // panels 4..7
    pack_f32_k<<<NDIM / 16, 256, 0, stream>>>(Wout, wop);

    // activation packs (fp32 -> packed bf16)
    pack_f32_k<<<NB / 16, 256, 0, stream>>>(latent, Lp);
    pack_f32_k<<<NB / 16, 256, 0, stream>>>(cond,   Cp);

    // Q projection (N=1024) and fused K|V projection (N=2048, W stacked)
    gemm256<0, 1024><<<1024, 512, 0, stream>>>(Lp, wqp,  nullptr, Qb);
    gemm256<0, 2048><<<2048, 512, 0, stream>>>(Cp, wkvp, nullptr, KVb);

    // attention: row-major Q/KV in, PACKED feats out (into Fp = Lp)
    attn_k<<<NB / 16, 1024, 0, stream>>>(Qb, KVb, Fp);

    // output projection reads packed feats
    gemm256<1, 1024><<<1024, 512, 0, stream>>>(Fp, wop, bout, out);
}